// Round 6
// baseline (77.895 us; speedup 1.0000x reference)
//
#include <hip/hip_runtime.h>
#include <cmath>

// Problem constants
#define BROWS 32768
#define SLEN  1024
#define TAILW 195
#define NB1   2048            // blocks; 4 waves each -> 8192 waves, 4 rows/wave
#define NWAVES (NB1 * 4)
#define RPW   4               // rows per wave
#define PART_STRIDE 2048      // partials laid out [7][2048] (transposed, coalesced reads)

__device__ __constant__ float c_decay_taus[4] = {40.0f, 300.0f, 230.0f, 2.4f};
__device__ __constant__ float c_rise_taus[4]  = {5.0f, 20.0f, 10.0f, 2.0f};

// Single fused kernel: per-row wave reduction (identical math to r5), per-wave
// 4-lane-parallel row epilogue, per-block partials, last-block final reduce.
extern "C" __global__ __launch_bounds__(256, 8)
void physics_fused(const float* __restrict__ wave,
                   const float* __restrict__ logits,
                   const int*   __restrict__ labels,
                   const float* __restrict__ amps,
                   double* __restrict__ partials,     // [7][PART_STRIDE]
                   unsigned* __restrict__ counter,    // zeroed by memset each launch
                   float* __restrict__ out)
{
    const int lane  = threadIdx.x & 63;
    const int wid   = threadIdx.x >> 6;
    const int gwave = blockIdx.x * 4 + wid;
    const int lane4 = lane * 4;
    const float4* base = reinterpret_cast<const float4*>(wave);

    __shared__ unsigned su[4][RPW][4];   // nSk(n|Sk<<8), Skk, csum bits, pki
    __shared__ double   sd[4][RPW][2];   // Sy, Sky
    __shared__ double   smp[4][7];       // per-wave loss partials
    __shared__ int      s_last;

    int row = gwave;
    const float4* p0 = base + (size_t)row * (SLEN / 4) + lane;
    float4 c0 = p0[0], c1 = p0[64], c2 = p0[128], c3 = p0[192];

    #pragma unroll
    for (int it = 0; it < RPW; ++it) {
        const int nrow = row + NWAVES;
        float4 n0, n1, n2, n3;
        if (it < RPW - 1) {                       // issue next-row loads EARLY
            const float4* pn = base + (size_t)nrow * (SLEN / 4) + lane;
            n0 = pn[0]; n1 = pn[64]; n2 = pn[128]; n3 = pn[192];
        }

        float vals[16] = {c0.x,c0.y,c0.z,c0.w, c1.x,c1.y,c1.z,c1.w,
                          c2.x,c2.y,c2.z,c2.w, c3.x,c3.y,c3.z,c3.w};

        // ---- pass 1: value-max (max3 tree) + relu-sum ----
        float m0 = fmaxf(fmaxf(vals[0],  vals[1]),  vals[2]);
        float m1 = fmaxf(fmaxf(vals[3],  vals[4]),  vals[5]);
        float m2 = fmaxf(fmaxf(vals[6],  vals[7]),  vals[8]);
        float m3 = fmaxf(fmaxf(vals[9],  vals[10]), vals[11]);
        float m4 = fmaxf(fmaxf(vals[12], vals[13]), fmaxf(vals[14], vals[15]));
        float bm = fmaxf(fmaxf(fmaxf(m0, m1), m2), fmaxf(m3, m4));

        float s0 = 0.f, s1 = 0.f, s2 = 0.f, s3 = 0.f;
        #pragma unroll
        for (int k = 0; k < 16; k += 4) {
            s0 += fmaxf(vals[k],     0.0f);
            s1 += fmaxf(vals[k + 1], 0.0f);
            s2 += fmaxf(vals[k + 2], 0.0f);
            s3 += fmaxf(vals[k + 3], 0.0f);
        }
        float csum = (s0 + s1) + (s2 + s3);

        // ---- interleaved butterflies: amp (max) + csum (sum) ----
        #pragma unroll
        for (int off = 1; off < 64; off <<= 1) {
            bm   = fmaxf(bm, __shfl_xor(bm, off, 64));
            csum += __shfl_xor(csum, off, 64);
        }
        const float amp = bm;

        // ---- peak = first index with w == amp, ballot + scalar ffs ----
        int peak = SLEN;
        #pragma unroll
        for (int q = 0; q < 4; ++q) {
            bool found = false;
            #pragma unroll
            for (int r = 0; r < 4; ++r) {
                const unsigned long long b = __ballot(vals[q * 4 + r] == amp);
                if (b) {
                    peak = min(peak, q * 256 + 4 * (__ffsll(b) - 1) + r);
                    found = true;
                }
            }
            if (found) break;
        }
        peak = __builtin_amdgcn_readfirstlane(peak);
        const bool do_decay = (peak < SLEN - 20);
        const int  pm5 = peak + 5;

        // ---- rise crossings via ballot & scalar lane-mask (j < peak) ----
        const float t10 = 0.1f * amp, t90 = 0.9f * amp;
        int i10 = SLEN, i90 = SLEN;
        #pragma unroll
        for (int q = 0; q < 4; ++q) {
            #pragma unroll
            for (int r = 0; r < 4; ++r) {
                const int jb = q * 256 + r;          // j = jb + 4*lane
                const int d  = peak - jb;            // lanes with 4*lane < d
                if (d > 0) {                         // uniform
                    const int lc = min(64, (d + 3) >> 2);
                    const unsigned long long lm =
                        (lc >= 64) ? ~0ull : ((1ull << lc) - 1ull);
                    const float w = vals[q * 4 + r];
                    const unsigned long long b10 = __ballot(w >= t10) & lm;
                    const unsigned long long b90 = __ballot(w >= t90) & lm;
                    if (b10) i10 = min(i10, jb + 4 * (__ffsll(b10) - 1));
                    if (b90) i90 = min(i90, jb + 4 * (__ffsll(b90) - 1));
                }
            }
        }

        // ---- decay regression sums over the <=2 intersecting quarters ----
        unsigned nSk_p = 0, Skk = 0;     // nSk_p = n | (Sk<<8); n<=195, Sk<=18915
        double Sy = 0.0, Sky = 0.0;
        if (do_decay) {                              // uniform
            #pragma unroll
            for (int q = 0; q < 4; ++q) {
                if (q * 256 + 255 >= pm5 && q * 256 <= pm5 + (TAILW - 1)) {  // uniform
                    #pragma unroll
                    for (int r = 0; r < 4; ++r) {
                        const int kk = q * 256 + lane4 + r - pm5;
                        const float w = vals[q * 4 + r];
                        if ((unsigned)kk < (unsigned)TAILW && w > 0.0f) {
                            const float y = __logf(w + 1e-8f);   // native v_log_f32
                            nSk_p += 1u + ((unsigned)kk << 8);
                            Skk   += (unsigned)(kk * kk);
                            Sy  += (double)y;
                            Sky += (double)kk * (double)y;
                        }
                    }
                }
            }
        }

        // ---- single butterfly for the 4 remaining quantities ----
        #pragma unroll
        for (int off = 1; off < 64; off <<= 1) {
            nSk_p += __shfl_xor(nSk_p, off, 64);
            Skk   += __shfl_xor(Skk,   off, 64);
            Sy    += __shfl_xor(Sy,    off, 64);
            Sky   += __shfl_xor(Sky,   off, 64);
        }

        if (lane == 0) {
            su[wid][it][0] = nSk_p;
            su[wid][it][1] = Skk;
            su[wid][it][2] = __float_as_uint(csum);
            su[wid][it][3] = ((unsigned)peak << 22) | ((unsigned)i10 << 11) | (unsigned)i90;
            sd[wid][it][0] = Sy;
            sd[wid][it][1] = Sky;
        }

        if (it < RPW - 1) { c0 = n0; c1 = n1; c2 = n2; c3 = n3; row = nrow; }
    }

    // ---- per-wave epilogue: lanes 0..3 finalize one row each (wave-local LDS,
    //      no barrier needed: same wave wrote it) ----
    double v0 = 0, v1 = 0, v2 = 0, v3 = 0, v4 = 0, v5 = 0, v6 = 0;
    if (lane < RPW) {
        const int r = gwave + lane * NWAVES;
        const unsigned nSk = su[wid][lane][0];
        const unsigned Skk = su[wid][lane][1];
        const float   csum = __uint_as_float(su[wid][lane][2]);
        const unsigned pki = su[wid][lane][3];
        const double  Sy   = sd[wid][lane][0];
        const double  Sky  = sd[wid][lane][1];
        const unsigned n_u  = nSk & 0xFFu;
        const unsigned Sk_u = nSk >> 8;
        const int peak = (int)(pki >> 22);
        const int i10  = (int)((pki >> 11) & 0x7FFu);
        const int i90  = (int)(pki & 0x7FFu);

        // CE + predicted class (library expf/logf for accuracy)
        const float4 l4 = reinterpret_cast<const float4*>(logits)[r];
        float lg[4] = {l4.x, l4.y, l4.z, l4.w};
        int pred = 0; float pbest = lg[0];
        #pragma unroll
        for (int c = 1; c < 4; ++c) if (lg[c] > pbest) { pbest = lg[c]; pred = c; }
        const float m = fmaxf(fmaxf(lg[0], lg[1]), fmaxf(lg[2], lg[3]));
        const float sexp = expf(lg[0] - m) + expf(lg[1] - m)
                         + expf(lg[2] - m) + expf(lg[3] - m);
        const float lse = m + logf(sexp);
        v0 = (double)(lse - lg[labels[r]]);

        // decay loss (f64 combine — slope/tau cancellation-sensitive)
        if (peak < SLEN - 20 && n_u >= 5u) {
            const double dn  = (double)n_u;
            const double dSk = (double)Sk_u;
            const double num = Sky - dSk * Sy / dn;             // DT_NS factored out
            const double den = 8.0 * ((double)Skk - dSk * dSk / dn);
            if (den > 0.0) {
                const double slope = num / fmax(den, 1e-30);
                const double tau   = -1.0 / (slope + 1e-8);
                const double d     = tau - (double)c_decay_taus[pred];
                v1 = d * d; v2 = 1.0;
            }
        }
        // rise loss
        if (peak >= 10 && i10 < SLEN && i90 < SLEN) {
            const float rise = (float)(i90 - i10) * 8.0f;
            const float er   = c_rise_taus[pred];
            v3 = (double)(fabsf(rise - er) / er); v4 = 1.0;
        }
        // energy ratio moments
        v5 = (double)csum / ((double)amps[r] + 1e-8);
        v6 = v5 * v5;
    }
    // reduce lanes 0..3 (other lanes hold zeros)
    #pragma unroll
    for (int off = 1; off <= 2; off <<= 1) {
        v0 += __shfl_xor(v0, off, 64);
        v1 += __shfl_xor(v1, off, 64);
        v2 += __shfl_xor(v2, off, 64);
        v3 += __shfl_xor(v3, off, 64);
        v4 += __shfl_xor(v4, off, 64);
        v5 += __shfl_xor(v5, off, 64);
        v6 += __shfl_xor(v6, off, 64);
    }
    if (lane == 0) {
        smp[wid][0] = v0; smp[wid][1] = v1; smp[wid][2] = v2; smp[wid][3] = v3;
        smp[wid][4] = v4; smp[wid][5] = v5; smp[wid][6] = v6;
    }
    __syncthreads();
    if (threadIdx.x < 7) {
        const int i = threadIdx.x;
        const double t = smp[0][i] + smp[1][i] + smp[2][i] + smp[3][i];
        __hip_atomic_store(&partials[(size_t)i * PART_STRIDE + blockIdx.x], t,
                           __ATOMIC_RELAXED, __HIP_MEMORY_SCOPE_AGENT);
    }
    __syncthreads();
    if (threadIdx.x == 0) {
        const unsigned prev = __hip_atomic_fetch_add(counter, 1u,
                                  __ATOMIC_ACQ_REL, __HIP_MEMORY_SCOPE_AGENT);
        s_last = (prev == NB1 - 1) ? 1 : 0;
    }
    __syncthreads();
    if (!s_last) return;

    // ---- last block: final reduce of [7][2048] partials + output ----
    double loc[7] = {0, 0, 0, 0, 0, 0, 0};
    #pragma unroll
    for (int k = 0; k < NB1 / 256; ++k) {
        const int b = k * 256 + threadIdx.x;
        #pragma unroll
        for (int i = 0; i < 7; ++i)
            loc[i] += __hip_atomic_load(&partials[(size_t)i * PART_STRIDE + b],
                                        __ATOMIC_RELAXED, __HIP_MEMORY_SCOPE_AGENT);
    }
    #pragma unroll
    for (int i = 0; i < 7; ++i) {
        #pragma unroll
        for (int off = 1; off < 64; off <<= 1)
            loc[i] += __shfl_xor(loc[i], off, 64);
    }
    if (lane == 0) {
        #pragma unroll
        for (int i = 0; i < 7; ++i) smp[wid][i] = loc[i];
    }
    __syncthreads();
    if (threadIdx.x == 0) {
        double t[7];
        #pragma unroll
        for (int i = 0; i < 7; ++i)
            t[i] = smp[0][i] + smp[1][i] + smp[2][i] + smp[3][i];
        const double Bn = (double)BROWS;
        const double ce    = t[0] / Bn;
        const double decay = (t[2] > 0.0) ? t[1] / fmax(t[2], 1.0) : 0.0;
        const double rise  = (t[4] > 0.0) ? t[3] / fmax(t[4], 1.0) : 0.0;
        const double var   = (t[6] - t[5] * t[5] / Bn) / (Bn - 1.0);  // ddof=1
        const double total = 0.7 * ce + 0.2 * decay + 0.1 * var + 0.05 * rise;
        out[0] = (float)total; out[1] = (float)ce; out[2] = (float)decay;
        out[3] = (float)var;   out[4] = (float)rise;
    }
}

extern "C" void kernel_launch(void* const* d_in, const int* in_sizes, int n_in,
                              void* d_out, int out_size, void* d_ws, size_t ws_size,
                              hipStream_t stream) {
    const float* logits = (const float*)d_in[0];
    const int*   labels = (const int*)d_in[1];
    const float* wave   = (const float*)d_in[2];
    const float* amps   = (const float*)d_in[3];

    double*   partials = (double*)d_ws;                       // 7*2048*8 = 114688 B
    unsigned* counter  = (unsigned*)((char*)d_ws + 7 * PART_STRIDE * sizeof(double));

    hipMemsetAsync(counter, 0, sizeof(unsigned), stream);     // graph-capturable
    physics_fused<<<NB1, 256, 0, stream>>>(wave, logits, labels, amps,
                                           partials, counter, (float*)d_out);
}

// Round 7
// 45.157 us; speedup vs baseline: 1.7250x; 1.7250x over previous
//
#include <hip/hip_runtime.h>
#include <cmath>

// Problem constants
#define BROWS 32768
#define SLEN  1024
#define TAILW 195
#define NB1   8192            // rows kernel: 8192 blocks x 4 waves = 32768 waves, 1 row/wave
#define NB2   128             // rowfin: 128 blocks x 256 threads, 1 row/thread
#define PSTRIDE 128           // partials [7][128]

__device__ __constant__ float c_decay_taus[4] = {40.0f, 300.0f, 230.0f, 2.4f};
__device__ __constant__ float c_rise_taus[4]  = {5.0f, 20.0f, 10.0f, 2.0f};

// Per-row stats, 32 B.
struct alignas(16) RowStat {
    unsigned nSk;   // n | (Sk<<16)
    unsigned Skk;
    float    csum;
    unsigned pki;   // (peak<<22)|(i10<<11)|i90
    double   Sy;
    double   Sky;
};

// Kernel 1: waveform-only, ONE ROW PER WAVE (pure TLP, no intra-wave row chain).
// Row math identical to r5: ballot+SALU index finding, <=2-quarter decay window,
// native v_log_f32 with f64 Sy/Sky accumulation.
extern "C" __global__ __launch_bounds__(256, 8)
void physics_rows(const float* __restrict__ wave, RowStat* __restrict__ stats)
{
    const int lane = threadIdx.x & 63;
    const int row  = (blockIdx.x * 256 + threadIdx.x) >> 6;   // 0..32767, 1 per wave
    const int lane4 = lane * 4;
    const float4* p = reinterpret_cast<const float4*>(wave) + (size_t)row * (SLEN / 4) + lane;

    const float4 c0 = p[0], c1 = p[64], c2 = p[128], c3 = p[192];
    float vals[16] = {c0.x,c0.y,c0.z,c0.w, c1.x,c1.y,c1.z,c1.w,
                      c2.x,c2.y,c2.z,c2.w, c3.x,c3.y,c3.z,c3.w};

    // ---- pass 1: value-max (max3 tree) + relu-sum ----
    float m0 = fmaxf(fmaxf(vals[0],  vals[1]),  vals[2]);
    float m1 = fmaxf(fmaxf(vals[3],  vals[4]),  vals[5]);
    float m2 = fmaxf(fmaxf(vals[6],  vals[7]),  vals[8]);
    float m3 = fmaxf(fmaxf(vals[9],  vals[10]), vals[11]);
    float m4 = fmaxf(fmaxf(vals[12], vals[13]), fmaxf(vals[14], vals[15]));
    float bm = fmaxf(fmaxf(fmaxf(m0, m1), m2), fmaxf(m3, m4));

    float s0 = 0.f, s1 = 0.f, s2 = 0.f, s3 = 0.f;
    #pragma unroll
    for (int k = 0; k < 16; k += 4) {
        s0 += fmaxf(vals[k],     0.0f);
        s1 += fmaxf(vals[k + 1], 0.0f);
        s2 += fmaxf(vals[k + 2], 0.0f);
        s3 += fmaxf(vals[k + 3], 0.0f);
    }
    float csum = (s0 + s1) + (s2 + s3);

    // ---- interleaved butterflies: amp (max) + csum (sum) ----
    #pragma unroll
    for (int off = 1; off < 64; off <<= 1) {
        bm   = fmaxf(bm, __shfl_xor(bm, off, 64));
        csum += __shfl_xor(csum, off, 64);
    }
    const float amp = bm;

    // ---- peak = first index with w == amp, ballot + scalar ffs (early exit) ----
    int peak = SLEN;
    #pragma unroll
    for (int q = 0; q < 4; ++q) {
        bool found = false;
        #pragma unroll
        for (int r = 0; r < 4; ++r) {
            const unsigned long long b = __ballot(vals[q * 4 + r] == amp);
            if (b) {
                peak = min(peak, q * 256 + 4 * (__ffsll(b) - 1) + r);
                found = true;
            }
        }
        if (found) break;
    }
    peak = __builtin_amdgcn_readfirstlane(peak);
    const bool do_decay = (peak < SLEN - 20);
    const int  pm5 = peak + 5;

    // ---- rise crossings via ballot & scalar lane-mask (j < peak) ----
    const float t10 = 0.1f * amp, t90 = 0.9f * amp;
    int i10 = SLEN, i90 = SLEN;
    #pragma unroll
    for (int q = 0; q < 4; ++q) {
        #pragma unroll
        for (int r = 0; r < 4; ++r) {
            const int jb = q * 256 + r;          // j = jb + 4*lane
            const int d  = peak - jb;            // lanes with 4*lane < d
            if (d > 0) {                         // uniform
                const int lc = min(64, (d + 3) >> 2);
                const unsigned long long lm =
                    (lc >= 64) ? ~0ull : ((1ull << lc) - 1ull);
                const float w = vals[q * 4 + r];
                const unsigned long long b10 = __ballot(w >= t10) & lm;
                const unsigned long long b90 = __ballot(w >= t90) & lm;
                if (b10) i10 = min(i10, jb + 4 * (__ffsll(b10) - 1));
                if (b90) i90 = min(i90, jb + 4 * (__ffsll(b90) - 1));
            }
        }
    }

    // ---- decay regression sums over the <=2 intersecting quarters ----
    unsigned nSk_p = 0, Skk = 0;     // nSk_p = n | (Sk<<8); n<=195, Sk<=18915
    double Sy = 0.0, Sky = 0.0;
    if (do_decay) {                              // uniform
        #pragma unroll
        for (int q = 0; q < 4; ++q) {
            if (q * 256 + 255 >= pm5 && q * 256 <= pm5 + (TAILW - 1)) {  // uniform
                #pragma unroll
                for (int r = 0; r < 4; ++r) {
                    const int kk = q * 256 + lane4 + r - pm5;
                    const float w = vals[q * 4 + r];
                    if ((unsigned)kk < (unsigned)TAILW && w > 0.0f) {
                        const float y = __logf(w + 1e-8f);   // native v_log_f32
                        nSk_p += 1u + ((unsigned)kk << 8);
                        Skk   += (unsigned)(kk * kk);
                        Sy  += (double)y;
                        Sky += (double)kk * (double)y;
                    }
                }
            }
        }
    }

    // ---- single butterfly for the 4 remaining quantities ----
    #pragma unroll
    for (int off = 1; off < 64; off <<= 1) {
        nSk_p += __shfl_xor(nSk_p, off, 64);
        Skk   += __shfl_xor(Skk,   off, 64);
        Sy    += __shfl_xor(Sy,    off, 64);
        Sky   += __shfl_xor(Sky,   off, 64);
    }

    if (lane == 0) {
        RowStat st;
        st.nSk  = (nSk_p & 0xFFu) | ((nSk_p >> 8) << 16);  // -> n | Sk<<16
        st.Skk  = Skk;
        st.csum = csum;
        st.pki  = ((unsigned)peak << 22) | ((unsigned)i10 << 11) | (unsigned)i90;
        st.Sy   = Sy;
        st.Sky  = Sky;
        stats[row] = st;
    }
}

// Kernel 2: one thread per row epilogue + block partials + last-block final
// reduce (atomic-counter pattern, validated in r6).
extern "C" __global__ __launch_bounds__(256)
void physics_rowfin(const RowStat* __restrict__ stats,
                    const float* __restrict__ logits,
                    const int* __restrict__ labels,
                    const float* __restrict__ amps,
                    double* __restrict__ partials,     // [7][PSTRIDE]
                    unsigned* __restrict__ counter,    // zeroed by memset each launch
                    float* __restrict__ out)
{
    const int r    = blockIdx.x * 256 + threadIdx.x;   // always < BROWS
    const int lane = threadIdx.x & 63;
    const int wid  = threadIdx.x >> 6;

    __shared__ double sm[4][7];
    __shared__ int s_last;

    const RowStat st = stats[r];
    const unsigned n_u  = st.nSk & 0xFFFFu;
    const unsigned Sk_u = st.nSk >> 16;
    const int peak = (int)(st.pki >> 22);
    const int i10  = (int)((st.pki >> 11) & 0x7FFu);
    const int i90  = (int)(st.pki & 0x7FFu);

    // CE + predicted class (library expf/logf — accuracy matters here)
    const float4 l4 = reinterpret_cast<const float4*>(logits)[r];
    float lg[4] = {l4.x, l4.y, l4.z, l4.w};
    int pred = 0; float pbest = lg[0];
    #pragma unroll
    for (int c = 1; c < 4; ++c) if (lg[c] > pbest) { pbest = lg[c]; pred = c; }
    const float m = fmaxf(fmaxf(lg[0], lg[1]), fmaxf(lg[2], lg[3]));
    const float sexp = expf(lg[0] - m) + expf(lg[1] - m)
                     + expf(lg[2] - m) + expf(lg[3] - m);
    const float lse = m + logf(sexp);
    const double v0 = (double)(lse - lg[labels[r]]);

    // decay loss (f64 combine — slope/tau cancellation-sensitive)
    double v1 = 0.0, v2 = 0.0;
    if (peak < SLEN - 20 && n_u >= 5u) {
        const double dn  = (double)n_u;
        const double dSk = (double)Sk_u;
        const double num = st.Sky - dSk * st.Sy / dn;           // DT_NS factored out
        const double den = 8.0 * ((double)st.Skk - dSk * dSk / dn);
        if (den > 0.0) {
            const double slope = num / fmax(den, 1e-30);
            const double tau   = -1.0 / (slope + 1e-8);
            const double d     = tau - (double)c_decay_taus[pred];
            v1 = d * d; v2 = 1.0;
        }
    }
    // rise loss
    double v3 = 0.0, v4 = 0.0;
    if (peak >= 10 && i10 < SLEN && i90 < SLEN) {
        const float rise = (float)(i90 - i10) * 8.0f;
        const float er   = c_rise_taus[pred];
        v3 = (double)(fabsf(rise - er) / er); v4 = 1.0;
    }
    // energy ratio moments
    const double ratio = (double)st.csum / ((double)amps[r] + 1e-8);

    double v[7] = {v0, v1, v2, v3, v4, ratio, ratio * ratio};
    #pragma unroll
    for (int i = 0; i < 7; ++i) {
        #pragma unroll
        for (int off = 1; off < 64; off <<= 1)
            v[i] += __shfl_xor(v[i], off, 64);
    }
    if (lane == 0) {
        #pragma unroll
        for (int i = 0; i < 7; ++i) sm[wid][i] = v[i];
    }
    __syncthreads();
    if (threadIdx.x < 7) {
        const int i = threadIdx.x;
        const double t = sm[0][i] + sm[1][i] + sm[2][i] + sm[3][i];
        __hip_atomic_store(&partials[(size_t)i * PSTRIDE + blockIdx.x], t,
                           __ATOMIC_RELAXED, __HIP_MEMORY_SCOPE_AGENT);
    }
    __syncthreads();
    if (threadIdx.x == 0) {
        const unsigned prev = __hip_atomic_fetch_add(counter, 1u,
                                  __ATOMIC_ACQ_REL, __HIP_MEMORY_SCOPE_AGENT);
        s_last = (prev == NB2 - 1) ? 1 : 0;
    }
    __syncthreads();
    if (!s_last) return;

    // ---- last block: reduce [7][128] partials, write the 5 outputs ----
    double loc[7] = {0, 0, 0, 0, 0, 0, 0};
    if (threadIdx.x < PSTRIDE) {
        #pragma unroll
        for (int i = 0; i < 7; ++i)
            loc[i] = __hip_atomic_load(&partials[(size_t)i * PSTRIDE + threadIdx.x],
                                       __ATOMIC_RELAXED, __HIP_MEMORY_SCOPE_AGENT);
    }
    #pragma unroll
    for (int i = 0; i < 7; ++i) {
        #pragma unroll
        for (int off = 1; off < 64; off <<= 1)
            loc[i] += __shfl_xor(loc[i], off, 64);
    }
    __syncthreads();                       // reuse sm safely
    if (lane == 0 && wid < 2) {
        #pragma unroll
        for (int i = 0; i < 7; ++i) sm[wid][i] = loc[i];
    }
    __syncthreads();
    if (threadIdx.x == 0) {
        double t[7];
        #pragma unroll
        for (int i = 0; i < 7; ++i) t[i] = sm[0][i] + sm[1][i];
        const double Bn = (double)BROWS;
        const double ce    = t[0] / Bn;
        const double decay = (t[2] > 0.0) ? t[1] / fmax(t[2], 1.0) : 0.0;
        const double rise  = (t[4] > 0.0) ? t[3] / fmax(t[4], 1.0) : 0.0;
        const double var   = (t[6] - t[5] * t[5] / Bn) / (Bn - 1.0);  // ddof=1
        const double total = 0.7 * ce + 0.2 * decay + 0.1 * var + 0.05 * rise;
        out[0] = (float)total; out[1] = (float)ce; out[2] = (float)decay;
        out[3] = (float)var;   out[4] = (float)rise;
    }
}

extern "C" void kernel_launch(void* const* d_in, const int* in_sizes, int n_in,
                              void* d_out, int out_size, void* d_ws, size_t ws_size,
                              hipStream_t stream) {
    const float* logits = (const float*)d_in[0];
    const int*   labels = (const int*)d_in[1];
    const float* wave   = (const float*)d_in[2];
    const float* amps   = (const float*)d_in[3];

    RowStat*  stats    = (RowStat*)d_ws;                                  // 1 MiB
    double*   partials = (double*)((char*)d_ws + (size_t)BROWS * sizeof(RowStat));
    unsigned* counter  = (unsigned*)((char*)partials + 7 * PSTRIDE * sizeof(double));

    hipMemsetAsync(counter, 0, sizeof(unsigned), stream);
    physics_rows<<<NB1, 256, 0, stream>>>(wave, stats);
    physics_rowfin<<<NB2, 256, 0, stream>>>(stats, logits, labels, amps,
                                            partials, counter, (float*)d_out);
}

// Round 8
// 39.647 us; speedup vs baseline: 1.9647x; 1.1390x over previous
//
#include <hip/hip_runtime.h>
#include <cmath>

// Problem constants
#define BROWS 32768
#define SLEN  1024
#define TAILW 195
#define NB1   8192            // rows kernel: 8192 blocks x 4 waves = 32768 waves, 1 row/wave
#define NB2   128             // rowfin: 128 blocks x 256 threads, 1 row/thread
#define PSTRIDE 128           // partials [7][128]

__device__ __constant__ float c_decay_taus[4] = {40.0f, 300.0f, 230.0f, 2.4f};
__device__ __constant__ float c_rise_taus[4]  = {5.0f, 20.0f, 10.0f, 2.0f};

// Per-row stats, 32 B.
struct alignas(16) RowStat {
    unsigned nSk;   // n | (Sk<<16)
    unsigned Skk;
    float    csum;
    unsigned pki;   // (peak<<22)|(i10<<11)|i90
    double   Sy;
    double   Sky;
};

// ---- DPP wave-reduction helpers (pure VALU, no LDS unit) ----
// Sequence row_shr:1,2,4,8 + row_bcast:15 + row_bcast:31 leaves the full
// 64-lane reduction in lane 63.  bound_ctrl=1 (invalid lanes -> 0) for sums;
// old=x (invalid lanes -> x, identity) for max.
template<int CTRL>
__device__ __forceinline__ unsigned dpp0_u32(unsigned x) {
    return (unsigned)__builtin_amdgcn_update_dpp(0, (int)x, CTRL, 0xf, 0xf, true);
}
template<int CTRL>
__device__ __forceinline__ float dpp0_f32(float x) {
    return __int_as_float(
        __builtin_amdgcn_update_dpp(0, __float_as_int(x), CTRL, 0xf, 0xf, true));
}
template<int CTRL>
__device__ __forceinline__ float dppid_f32(float x) {
    return __int_as_float(__builtin_amdgcn_update_dpp(
        __float_as_int(x), __float_as_int(x), CTRL, 0xf, 0xf, false));
}
template<int CTRL>
__device__ __forceinline__ double dpp0_f64(double x) {
    const int lo = __builtin_amdgcn_update_dpp(0, __double2loint(x), CTRL, 0xf, 0xf, true);
    const int hi = __builtin_amdgcn_update_dpp(0, __double2hiint(x), CTRL, 0xf, 0xf, true);
    return __hiloint2double(hi, lo);
}
#define ROW_SHR1  0x111
#define ROW_SHR2  0x112
#define ROW_SHR4  0x114
#define ROW_SHR8  0x118
#define BCAST15   0x142
#define BCAST31   0x143
#define WSUM_F32(x) { x += dpp0_f32<ROW_SHR1>(x); x += dpp0_f32<ROW_SHR2>(x); \
                      x += dpp0_f32<ROW_SHR4>(x); x += dpp0_f32<ROW_SHR8>(x); \
                      x += dpp0_f32<BCAST15>(x);  x += dpp0_f32<BCAST31>(x); }
#define WSUM_U32(x) { x += dpp0_u32<ROW_SHR1>(x); x += dpp0_u32<ROW_SHR2>(x); \
                      x += dpp0_u32<ROW_SHR4>(x); x += dpp0_u32<ROW_SHR8>(x); \
                      x += dpp0_u32<BCAST15>(x);  x += dpp0_u32<BCAST31>(x); }
#define WSUM_F64(x) { x += dpp0_f64<ROW_SHR1>(x); x += dpp0_f64<ROW_SHR2>(x); \
                      x += dpp0_f64<ROW_SHR4>(x); x += dpp0_f64<ROW_SHR8>(x); \
                      x += dpp0_f64<BCAST15>(x);  x += dpp0_f64<BCAST31>(x); }
#define WMAX_F32(x) { x = fmaxf(x, dppid_f32<ROW_SHR1>(x)); x = fmaxf(x, dppid_f32<ROW_SHR2>(x)); \
                      x = fmaxf(x, dppid_f32<ROW_SHR4>(x)); x = fmaxf(x, dppid_f32<ROW_SHR8>(x)); \
                      x = fmaxf(x, dppid_f32<BCAST15>(x));  x = fmaxf(x, dppid_f32<BCAST31>(x)); }

// Kernel 1: waveform-only, one row per wave. DPP reductions (no DS unit),
// ballot+uniform-SALU index finding with quarter-level early exit.
extern "C" __global__ __launch_bounds__(256, 8)
void physics_rows(const float* __restrict__ wave, RowStat* __restrict__ stats)
{
    const int lane = threadIdx.x & 63;
    const int row  = (blockIdx.x * 256 + threadIdx.x) >> 6;   // 1 row per wave
    const int lane4 = lane * 4;
    const float4* p = reinterpret_cast<const float4*>(wave) + (size_t)row * (SLEN / 4) + lane;

    const float4 c0 = p[0], c1 = p[64], c2 = p[128], c3 = p[192];
    float vals[16] = {c0.x,c0.y,c0.z,c0.w, c1.x,c1.y,c1.z,c1.w,
                      c2.x,c2.y,c2.z,c2.w, c3.x,c3.y,c3.z,c3.w};

    // ---- pass 1: per-lane value-max + relu-sum ----
    float m0 = fmaxf(fmaxf(vals[0],  vals[1]),  vals[2]);
    float m1 = fmaxf(fmaxf(vals[3],  vals[4]),  vals[5]);
    float m2 = fmaxf(fmaxf(vals[6],  vals[7]),  vals[8]);
    float m3 = fmaxf(fmaxf(vals[9],  vals[10]), vals[11]);
    float m4 = fmaxf(fmaxf(vals[12], vals[13]), fmaxf(vals[14], vals[15]));
    float bm = fmaxf(fmaxf(fmaxf(m0, m1), m2), fmaxf(m3, m4));

    float s0 = 0.f, s1 = 0.f, s2 = 0.f, s3 = 0.f;
    #pragma unroll
    for (int k = 0; k < 16; k += 4) {
        s0 += fmaxf(vals[k],     0.0f);
        s1 += fmaxf(vals[k + 1], 0.0f);
        s2 += fmaxf(vals[k + 2], 0.0f);
        s3 += fmaxf(vals[k + 3], 0.0f);
    }
    float csum = (s0 + s1) + (s2 + s3);

    // ---- DPP wave reductions: amp (max, broadcast via readlane), csum ----
    WMAX_F32(bm);
    WSUM_F32(csum);                       // valid in lane 63 only
    const float amp = __int_as_float(
        __builtin_amdgcn_readlane(__float_as_int(bm), 63));

    // ---- peak = first index with w == amp (ballot + uniform SALU, early exit) ----
    int peak = SLEN;
    #pragma unroll
    for (int q = 0; q < 4; ++q) {
        bool found = false;
        #pragma unroll
        for (int r = 0; r < 4; ++r) {
            const unsigned long long b = __ballot(vals[q * 4 + r] == amp);
            if (b) {
                peak = min(peak, q * 256 + 4 * (__ffsll(b) - 1) + r);
                found = true;
            }
        }
        if (found) break;
    }
    peak = __builtin_amdgcn_readfirstlane(peak);
    const bool do_decay = (peak < SLEN - 20);
    const int  pm5 = peak + 5;

    // ---- rise crossings: unmasked ballots, quarter-at-a-time uniform scan ----
    const float t10v = 0.1f * amp, t90v = 0.9f * amp;
    int i10 = SLEN, i90 = SLEN;
    const int q_peak = peak >> 8;
    #pragma unroll
    for (int q = 0; q < 4; ++q) {
        if (q > q_peak || (i10 < SLEN && i90 < SLEN)) break;   // uniform
        const int qb = q * 256;
        unsigned long long m10[4], m90[4];
        #pragma unroll
        for (int r = 0; r < 4; ++r) {
            m10[r] = __ballot(vals[q * 4 + r] >= t10v);
            m90[r] = __ballot(vals[q * 4 + r] >= t90v);
        }
        if (q == q_peak) {                 // boundary quarter: mask to j < peak
            #pragma unroll
            for (int r = 0; r < 4; ++r) {
                const int cnt = (peak - qb - r + 3) >> 2;
                const unsigned long long lm =
                    (cnt >= 64) ? ~0ull : ((cnt <= 0) ? 0ull : ((1ull << cnt) - 1ull));
                m10[r] &= lm; m90[r] &= lm;
            }
        }
        if (i10 == SLEN) {
            int best = SLEN;
            #pragma unroll
            for (int r = 0; r < 4; ++r)
                if (m10[r]) best = min(best, qb + 4 * (__ffsll(m10[r]) - 1) + r);
            i10 = best;
        }
        if (i90 == SLEN) {
            int best = SLEN;
            #pragma unroll
            for (int r = 0; r < 4; ++r)
                if (m90[r]) best = min(best, qb + 4 * (__ffsll(m90[r]) - 1) + r);
            i90 = best;
        }
    }

    // ---- decay regression sums over the <=2 intersecting quarters ----
    unsigned nSk_p = 0, Skk = 0;     // nSk_p = n | (Sk<<8); n<=195, Sk<=18915
    double Sy = 0.0, Sky = 0.0;
    if (do_decay) {                              // uniform
        #pragma unroll
        for (int q = 0; q < 4; ++q) {
            if (q * 256 + 255 >= pm5 && q * 256 <= pm5 + (TAILW - 1)) {  // uniform
                #pragma unroll
                for (int r = 0; r < 4; ++r) {
                    const int kk = q * 256 + lane4 + r - pm5;
                    const float w = vals[q * 4 + r];
                    if ((unsigned)kk < (unsigned)TAILW && w > 0.0f) {
                        const float y = __logf(w + 1e-8f);   // native v_log_f32
                        nSk_p += 1u + ((unsigned)kk << 8);
                        Skk   += (unsigned)(kk * kk);
                        Sy  += (double)y;
                        Sky += (double)kk * (double)y;
                    }
                }
            }
        }
    }

    // ---- DPP reductions for the 4 remaining quantities (f64 via halves) ----
    WSUM_U32(nSk_p);
    WSUM_U32(Skk);
    WSUM_F64(Sy);
    WSUM_F64(Sky);

    if (lane == 63) {
        RowStat st;
        st.nSk  = (nSk_p & 0xFFu) | ((nSk_p >> 8) << 16);  // -> n | Sk<<16
        st.Skk  = Skk;
        st.csum = csum;
        st.pki  = ((unsigned)peak << 22) | ((unsigned)i10 << 11) | (unsigned)i90;
        st.Sy   = Sy;
        st.Sky  = Sky;
        stats[row] = st;
    }
}

// Kernel 2: one thread per row epilogue + block partials + last-block final
// reduce (atomic-counter pattern).
extern "C" __global__ __launch_bounds__(256)
void physics_rowfin(const RowStat* __restrict__ stats,
                    const float* __restrict__ logits,
                    const int* __restrict__ labels,
                    const float* __restrict__ amps,
                    double* __restrict__ partials,     // [7][PSTRIDE]
                    unsigned* __restrict__ counter,    // zeroed by memset each launch
                    float* __restrict__ out)
{
    const int r    = blockIdx.x * 256 + threadIdx.x;   // always < BROWS
    const int lane = threadIdx.x & 63;
    const int wid  = threadIdx.x >> 6;

    __shared__ double sm[4][7];
    __shared__ int s_last;

    const RowStat st = stats[r];
    const unsigned n_u  = st.nSk & 0xFFFFu;
    const unsigned Sk_u = st.nSk >> 16;
    const int peak = (int)(st.pki >> 22);
    const int i10  = (int)((st.pki >> 11) & 0x7FFu);
    const int i90  = (int)(st.pki & 0x7FFu);

    // CE + predicted class (library expf/logf — accuracy matters here)
    const float4 l4 = reinterpret_cast<const float4*>(logits)[r];
    float lg[4] = {l4.x, l4.y, l4.z, l4.w};
    int pred = 0; float pbest = lg[0];
    #pragma unroll
    for (int c = 1; c < 4; ++c) if (lg[c] > pbest) { pbest = lg[c]; pred = c; }
    const float m = fmaxf(fmaxf(lg[0], lg[1]), fmaxf(lg[2], lg[3]));
    const float sexp = expf(lg[0] - m) + expf(lg[1] - m)
                     + expf(lg[2] - m) + expf(lg[3] - m);
    const float lse = m + logf(sexp);
    const double v0 = (double)(lse - lg[labels[r]]);

    // decay loss (f64 combine — slope/tau cancellation-sensitive)
    double v1 = 0.0, v2 = 0.0;
    if (peak < SLEN - 20 && n_u >= 5u) {
        const double dn  = (double)n_u;
        const double dSk = (double)Sk_u;
        const double num = st.Sky - dSk * st.Sy / dn;           // DT_NS factored out
        const double den = 8.0 * ((double)st.Skk - dSk * dSk / dn);
        if (den > 0.0) {
            const double slope = num / fmax(den, 1e-30);
            const double tau   = -1.0 / (slope + 1e-8);
            const double d     = tau - (double)c_decay_taus[pred];
            v1 = d * d; v2 = 1.0;
        }
    }
    // rise loss
    double v3 = 0.0, v4 = 0.0;
    if (peak >= 10 && i10 < SLEN && i90 < SLEN) {
        const float rise = (float)(i90 - i10) * 8.0f;
        const float er   = c_rise_taus[pred];
        v3 = (double)(fabsf(rise - er) / er); v4 = 1.0;
    }
    // energy ratio moments
    const double ratio = (double)st.csum / ((double)amps[r] + 1e-8);

    double v[7] = {v0, v1, v2, v3, v4, ratio, ratio * ratio};
    #pragma unroll
    for (int i = 0; i < 7; ++i) {
        #pragma unroll
        for (int off = 1; off < 64; off <<= 1)
            v[i] += __shfl_xor(v[i], off, 64);
    }
    if (lane == 0) {
        #pragma unroll
        for (int i = 0; i < 7; ++i) sm[wid][i] = v[i];
    }
    __syncthreads();
    if (threadIdx.x < 7) {
        const int i = threadIdx.x;
        const double t = sm[0][i] + sm[1][i] + sm[2][i] + sm[3][i];
        __hip_atomic_store(&partials[(size_t)i * PSTRIDE + blockIdx.x], t,
                           __ATOMIC_RELAXED, __HIP_MEMORY_SCOPE_AGENT);
    }
    __syncthreads();
    if (threadIdx.x == 0) {
        const unsigned prev = __hip_atomic_fetch_add(counter, 1u,
                                  __ATOMIC_ACQ_REL, __HIP_MEMORY_SCOPE_AGENT);
        s_last = (prev == NB2 - 1) ? 1 : 0;
    }
    __syncthreads();
    if (!s_last) return;

    // ---- last block: reduce [7][128] partials, write the 5 outputs ----
    double loc[7] = {0, 0, 0, 0, 0, 0, 0};
    if (threadIdx.x < PSTRIDE) {
        #pragma unroll
        for (int i = 0; i < 7; ++i)
            loc[i] = __hip_atomic_load(&partials[(size_t)i * PSTRIDE + threadIdx.x],
                                       __ATOMIC_RELAXED, __HIP_MEMORY_SCOPE_AGENT);
    }
    #pragma unroll
    for (int i = 0; i < 7; ++i) {
        #pragma unroll
        for (int off = 1; off < 64; off <<= 1)
            loc[i] += __shfl_xor(loc[i], off, 64);
    }
    __syncthreads();                       // reuse sm safely
    if (lane == 0 && wid < 2) {
        #pragma unroll
        for (int i = 0; i < 7; ++i) sm[wid][i] = loc[i];
    }
    __syncthreads();
    if (threadIdx.x == 0) {
        double t[7];
        #pragma unroll
        for (int i = 0; i < 7; ++i) t[i] = sm[0][i] + sm[1][i];
        const double Bn = (double)BROWS;
        const double ce    = t[0] / Bn;
        const double decay = (t[2] > 0.0) ? t[1] / fmax(t[2], 1.0) : 0.0;
        const double rise  = (t[4] > 0.0) ? t[3] / fmax(t[4], 1.0) : 0.0;
        const double var   = (t[6] - t[5] * t[5] / Bn) / (Bn - 1.0);  // ddof=1
        const double total = 0.7 * ce + 0.2 * decay + 0.1 * var + 0.05 * rise;
        out[0] = (float)total; out[1] = (float)ce; out[2] = (float)decay;
        out[3] = (float)var;   out[4] = (float)rise;
    }
}

extern "C" void kernel_launch(void* const* d_in, const int* in_sizes, int n_in,
                              void* d_out, int out_size, void* d_ws, size_t ws_size,
                              hipStream_t stream) {
    const float* logits = (const float*)d_in[0];
    const int*   labels = (const int*)d_in[1];
    const float* wave   = (const float*)d_in[2];
    const float* amps   = (const float*)d_in[3];

    RowStat*  stats    = (RowStat*)d_ws;                                  // 1 MiB
    double*   partials = (double*)((char*)d_ws + (size_t)BROWS * sizeof(RowStat));
    unsigned* counter  = (unsigned*)((char*)partials + 7 * PSTRIDE * sizeof(double));

    hipMemsetAsync(counter, 0, sizeof(unsigned), stream);
    physics_rows<<<NB1, 256, 0, stream>>>(wave, stats);
    physics_rowfin<<<NB2, 256, 0, stream>>>(stats, logits, labels, amps,
                                            partials, counter, (float*)d_out);
}